// Round 3
// baseline (380.572 us; speedup 1.0000x reference)
//
#include <hip/hip_runtime.h>

// Axial 7x7 attention, fused. N=512, GRID=7, Cq=64, Cv=512, B=3584.
// qH,qW:(B,7,64) kH,kW:(B,64,7) vH,vW:(B,512,7) out:(N,512,7,7) fp32
// R3: thread=c phase D. acc[49] in VGPRs, v slabs via global_load_lds dbuf,
// probs as wave-uniform b128 broadcasts, out transposed through LDS.

#define NEGINF (-1e20f)

constexpr int QK_SLICE = 7 * 7 * 64;   // 3136
constexpr int V_SLICE  = 7 * 512 * 7;  // 25088

// LDS floats:
//  [0,14336)   V: v slab-pair double buffer (2 x 7168) | aliases qk stage
//              (qHs 3332 | kHs 3192 | qWs 3332 | kWs 3192 = 13048)
//              | aliases writeback buffer 256x51 = 13056
//  [14336,15120) P logits 49x16
//  [15120,15512) pHs 49x8 (transposed padded probs, H part)
//  [15512,15904) pWs 49x8
// total 15904 fl = 63616 B -> 2 blocks/CU

__device__ __forceinline__ void load_lds16(const float* g, float* l) {
    __builtin_amdgcn_global_load_lds(
        (const __attribute__((address_space(1))) unsigned int*)g,
        (__attribute__((address_space(3))) unsigned int*)l, 16, 0, 0);
}

__global__ __launch_bounds__(512, 4) void fused_axial(
    const float* __restrict__ qH, const float* __restrict__ kH,
    const float* __restrict__ vH, const float* __restrict__ qW,
    const float* __restrict__ kW, const float* __restrict__ vW,
    float* __restrict__ out)
{
    __shared__ float sm[15904];
    float* V   = sm;
    float* P   = sm + 14336;
    float* pHs = sm + 15120;
    float* pWs = sm + 15512;

    float* qHs = sm;
    float* kHs = sm + 3332;
    float* qWs = sm + 6524;
    float* kWs = sm + 9856;

    const int n = blockIdx.x;
    const int t = threadIdx.x;

    // ---- Phase A: stage q/k (coalesced float4) ----
    {
        const float* srcQH = qH + n * QK_SLICE;
        const float* srcKH = kH + n * QK_SLICE;
        const float* srcQW = qW + n * QK_SLICE;
        const float* srcKW = kW + n * QK_SLICE;
        for (int it = t; it < 784; it += 512) {
            int wh = it >> 4;
            int c  = (it & 15) << 2;
            float4 v0 = ((const float4*)srcQH)[it];
            *(float4*)(qHs + wh * 68 + c) = v0;
            float4 v1 = ((const float4*)srcQW)[it];
            *(float4*)(qWs + wh * 68 + c) = v1;
            int w = it / 112;
            int r = (it - w * 112) << 2;
            float4 v2 = ((const float4*)srcKH)[it];
            *(float4*)(kHs + w * 456 + r) = v2;
            float4 v3 = ((const float4*)srcKW)[it];
            *(float4*)(kWs + w * 456 + r) = v3;
        }
    }
    __syncthreads();

    // ---- Phase B: 686 dots -> logits in P ----
    for (int d = t; d < 686; d += 512) {
        const bool isH = d < 343;
        int dd = isH ? d : d - 343;
        int a   = dd / 49;
        int rem = dd - a * 49;
        int b   = rem / 7;
        int j   = rem - b * 7;
        const float* qrow  = (isH ? qHs : qWs) + (a * 7 + b) * 68;
        const float* kbase = (isH ? kHs : kWs) + a * 456 + j;
        float e = 0.f;
        #pragma unroll
        for (int c = 0; c < 64; c += 4) {
            float4 qv = *(const float4*)(qrow + c);
            e += qv.x * kbase[c * 7];
            e += qv.y * kbase[c * 7 + 7];
            e += qv.z * kbase[c * 7 + 14];
            e += qv.w * kbase[c * 7 + 21];
        }
        if (isH) {
            if (b == j) e = NEGINF;
            P[(b * 7 + a) * 16 + j] = e;
        } else {
            P[(a * 7 + b) * 16 + 7 + j] = e;
        }
    }
    __syncthreads();   // qk region dead from here on

    const float* vHn = vH + n * V_SLICE;
    const float* vWn = vW + n * V_SLICE;

    // prefetch slab-pair 0 into buf0 (latency hidden behind softmax + barrier)
    {
        const float* sH = vHn;          // vH[n][w=0][*][*]  3584 fl
        const float* sW = vWn;          // vW[n][h=0][*][*]
        #pragma unroll
        for (int k = 0; k < 4; ++k) {
            int id = t + 512 * k;
            if (id < 1792) {
                const float* g = (id < 896) ? sH + id * 4 : sW + (id - 896) * 4;
                load_lds16(g, V + id * 4);
            }
        }
    }

    // ---- Phase C: softmax, write transposed padded prob tables ----
    if (t < 49) {
        float* row = P + t * 16;
        float l[14];
        float m = -3.4e38f;
        #pragma unroll
        for (int k = 0; k < 14; ++k) { l[k] = row[k]; m = fmaxf(m, l[k]); }
        float s = 0.f;
        #pragma unroll
        for (int k = 0; k < 14; ++k) { l[k] = __expf(l[k] - m); s += l[k]; }
        float inv = 1.f / s;
        #pragma unroll
        for (int j = 0; j < 7; ++j) {
            pHs[t * 8 + j] = l[j] * inv;        // p(h,w, j)
            pWs[t * 8 + j] = l[7 + j] * inv;    // p(h,w, 7+j)
        }
    }
    __syncthreads();   // probs ready + slab0 landed (vmcnt drained by barrier)

    // ---- Phase D: thread t owns channel c=t; acc[h*7+w] in VGPRs ----
    float acc[49];
    #pragma unroll
    for (int k = 0; k < 49; ++k) acc[k] = 0.f;

    for (int i = 0; i < 7; ++i) {
        // prefetch slab-pair i+1 into the other buffer
        if (i < 6) {
            const float* sH = vHn + (i + 1) * 3584;
            const float* sW = vWn + (i + 1) * 3584;
            float* dst = V + ((i + 1) & 1) * 7168;
            #pragma unroll
            for (int k = 0; k < 4; ++k) {
                int id = t + 512 * k;
                if (id < 1792) {
                    const float* g = (id < 896) ? sH + id * 4 : sW + (id - 896) * 4;
                    load_lds16(g, dst + id * 4);
                }
            }
        }
        const float* cur = V + (i & 1) * 7168;
        float vh[7], vw[7];
        const float* hr = cur + t * 7;          // vH[n, w=i, c=t, :]
        const float* wr = cur + 3584 + t * 7;   // vW[n, h=i, c=t, :]
        #pragma unroll
        for (int j = 0; j < 7; ++j) { vh[j] = hr[j]; vw[j] = wr[j]; }

        #pragma unroll
        for (int h = 0; h < 7; ++h) {           // out[c, h, w=i] += pH . vh
            const float* pp = pHs + (h * 7 + i) * 8;
            float4 p0 = *(const float4*)pp;
            float4 p1 = *(const float4*)(pp + 4);
            acc[h * 7 + i] += p0.x * vh[0] + p0.y * vh[1] + p0.z * vh[2] +
                              p0.w * vh[3] + p1.x * vh[4] + p1.y * vh[5] +
                              p1.z * vh[6];
        }
        #pragma unroll
        for (int w = 0; w < 7; ++w) {           // out[c, h=i, w] += pW . vw
            const float* pp = pWs + (i * 7 + w) * 8;
            float4 p0 = *(const float4*)pp;
            float4 p1 = *(const float4*)(pp + 4);
            acc[i * 7 + w] += p0.x * vw[0] + p0.y * vw[1] + p0.z * vw[2] +
                              p0.w * vw[3] + p1.x * vw[4] + p1.y * vw[5] +
                              p1.z * vw[6];
        }
        __syncthreads();   // next buffer landed; cur reads done before overwrite
    }

    // ---- Phase E: transpose acc through LDS, coalesced float4 stores ----
    float* outn = out + n * V_SLICE;
    #pragma unroll
    for (int half = 0; half < 2; ++half) {
        if ((t >> 8) == half) {
            float* wb = V + (t & 255) * 51;
            #pragma unroll
            for (int k = 0; k < 49; ++k) wb[k] = acc[k];
        }
        __syncthreads();
        #pragma unroll
        for (int k = 0; k < 7; ++k) {
            int f4 = t + 512 * k;
            if (f4 < 3136) {
                int f = f4 * 4;
                float4 o;
                #pragma unroll
                for (int u = 0; u < 4; ++u) {
                    int e  = f + u;
                    int c  = e / 49;
                    int hw = e - c * 49;
                    ((float*)&o)[u] = V[c * 51 + hw];
                }
                *(float4*)(outn + half * 12544 + f) = o;
            }
        }
        __syncthreads();
    }
}

extern "C" void kernel_launch(void* const* d_in, const int* in_sizes, int n_in,
                              void* d_out, int out_size, void* d_ws, size_t ws_size,
                              hipStream_t stream) {
    const float* qH = (const float*)d_in[0];
    const float* kH = (const float*)d_in[1];
    const float* vH = (const float*)d_in[2];
    const float* qW = (const float*)d_in[3];
    const float* kW = (const float*)d_in[4];
    const float* vW = (const float*)d_in[5];
    float* out = (float*)d_out;
    fused_axial<<<512, 512, 0, stream>>>(qH, kH, vH, qW, kW, vW, out);
}

// Round 4
// 380.263 us; speedup vs baseline: 1.0008x; 1.0008x over previous
//
#include <hip/hip_runtime.h>

// Axial 7x7 attention, fused. N=512, GRID=7, Cq=64, Cv=512, B=3584.
// qH,qW:(B,7,64) kH,kW:(B,64,7) vH,vW:(B,512,7) out:(N,512,7,7) fp32
// R4: R3 + fully-unrolled slab loop so acc[49] registerizes (R3 spilled it:
// dynamic index -> scratch -> 879 MB HBM traffic).

#define NEGINF (-1e20f)

constexpr int QK_SLICE = 7 * 7 * 64;   // 3136
constexpr int V_SLICE  = 7 * 512 * 7;  // 25088

// LDS floats:
//  [0,14336)   V: v slab-pair double buffer (2 x 7168) | aliases qk stage
//              (qHs 3332 | kHs 3192 | qWs 3332 | kWs 3192 = 13048)
//              | aliases writeback buffer 256x51 = 13056
//  [14336,15120) P logits 49x16
//  [15120,15512) pHs 49x8 (transposed padded probs, H part)
//  [15512,15904) pWs 49x8
// total 15904 fl = 63616 B -> 2 blocks/CU

__device__ __forceinline__ void load_lds16(const float* g, float* l) {
    __builtin_amdgcn_global_load_lds(
        (const __attribute__((address_space(1))) unsigned int*)g,
        (__attribute__((address_space(3))) unsigned int*)l, 16, 0, 0);
}

__global__ __launch_bounds__(512, 4) void fused_axial(
    const float* __restrict__ qH, const float* __restrict__ kH,
    const float* __restrict__ vH, const float* __restrict__ qW,
    const float* __restrict__ kW, const float* __restrict__ vW,
    float* __restrict__ out)
{
    __shared__ float sm[15904];
    float* V   = sm;
    float* P   = sm + 14336;
    float* pHs = sm + 15120;
    float* pWs = sm + 15512;

    float* qHs = sm;
    float* kHs = sm + 3332;
    float* qWs = sm + 6524;
    float* kWs = sm + 9856;

    const int n = blockIdx.x;
    const int t = threadIdx.x;

    // ---- Phase A: stage q/k (coalesced float4) ----
    {
        const float* srcQH = qH + n * QK_SLICE;
        const float* srcKH = kH + n * QK_SLICE;
        const float* srcQW = qW + n * QK_SLICE;
        const float* srcKW = kW + n * QK_SLICE;
        for (int it = t; it < 784; it += 512) {
            int wh = it >> 4;
            int c  = (it & 15) << 2;
            float4 v0 = ((const float4*)srcQH)[it];
            *(float4*)(qHs + wh * 68 + c) = v0;
            float4 v1 = ((const float4*)srcQW)[it];
            *(float4*)(qWs + wh * 68 + c) = v1;
            int w = it / 112;
            int r = (it - w * 112) << 2;
            float4 v2 = ((const float4*)srcKH)[it];
            *(float4*)(kHs + w * 456 + r) = v2;
            float4 v3 = ((const float4*)srcKW)[it];
            *(float4*)(kWs + w * 456 + r) = v3;
        }
    }
    __syncthreads();

    // ---- Phase B: 686 dots -> logits in P ----
    for (int d = t; d < 686; d += 512) {
        const bool isH = d < 343;
        int dd = isH ? d : d - 343;
        int a   = dd / 49;
        int rem = dd - a * 49;
        int b   = rem / 7;
        int j   = rem - b * 7;
        const float* qrow  = (isH ? qHs : qWs) + (a * 7 + b) * 68;
        const float* kbase = (isH ? kHs : kWs) + a * 456 + j;
        float e = 0.f;
        #pragma unroll
        for (int c = 0; c < 64; c += 4) {
            float4 qv = *(const float4*)(qrow + c);
            e += qv.x * kbase[c * 7];
            e += qv.y * kbase[c * 7 + 7];
            e += qv.z * kbase[c * 7 + 14];
            e += qv.w * kbase[c * 7 + 21];
        }
        if (isH) {
            if (b == j) e = NEGINF;
            P[(b * 7 + a) * 16 + j] = e;
        } else {
            P[(a * 7 + b) * 16 + 7 + j] = e;
        }
    }
    __syncthreads();   // qk region dead from here on

    const float* vHn = vH + n * V_SLICE;
    const float* vWn = vW + n * V_SLICE;

    // prefetch slab-pair 0 into buf0 (latency hidden behind softmax + barrier)
    {
        const float* sH = vHn;          // vH[n][w=0][*][*]  3584 fl
        const float* sW = vWn;          // vW[n][h=0][*][*]
        #pragma unroll
        for (int k = 0; k < 4; ++k) {
            int id = t + 512 * k;
            if (id < 1792) {
                const float* g = (id < 896) ? sH + id * 4 : sW + (id - 896) * 4;
                load_lds16(g, V + id * 4);
            }
        }
    }

    // ---- Phase C: softmax, write transposed padded prob tables ----
    if (t < 49) {
        float* row = P + t * 16;
        float l[14];
        float m = -3.4e38f;
        #pragma unroll
        for (int k = 0; k < 14; ++k) { l[k] = row[k]; m = fmaxf(m, l[k]); }
        float s = 0.f;
        #pragma unroll
        for (int k = 0; k < 14; ++k) { l[k] = __expf(l[k] - m); s += l[k]; }
        float inv = 1.f / s;
        #pragma unroll
        for (int j = 0; j < 7; ++j) {
            pHs[t * 8 + j] = l[j] * inv;        // p(h,w, j)
            pWs[t * 8 + j] = l[7 + j] * inv;    // p(h,w, 7+j)
        }
    }
    __syncthreads();   // probs ready + slab0 landed (vmcnt drained by barrier)

    // ---- Phase D: thread t owns channel c=t; acc[h*7+w] in VGPRs ----
    float acc[49];
    #pragma unroll
    for (int k = 0; k < 49; ++k) acc[k] = 0.f;

    #pragma unroll 7                       // CRITICAL: constant acc indices
    for (int i = 0; i < 7; ++i) {
        // prefetch slab-pair i+1 into the other buffer
        if (i < 6) {
            const float* sH = vHn + (i + 1) * 3584;
            const float* sW = vWn + (i + 1) * 3584;
            float* dst = V + ((i + 1) & 1) * 7168;
            #pragma unroll
            for (int k = 0; k < 4; ++k) {
                int id = t + 512 * k;
                if (id < 1792) {
                    const float* g = (id < 896) ? sH + id * 4 : sW + (id - 896) * 4;
                    load_lds16(g, dst + id * 4);
                }
            }
        }
        const float* cur = V + (i & 1) * 7168;
        float vh[7], vw[7];
        const float* hr = cur + t * 7;          // vH[n, w=i, c=t, :]
        const float* wr = cur + 3584 + t * 7;   // vW[n, h=i, c=t, :]
        #pragma unroll
        for (int j = 0; j < 7; ++j) { vh[j] = hr[j]; vw[j] = wr[j]; }

        #pragma unroll
        for (int h = 0; h < 7; ++h) {           // out[c, h, w=i] += pH . vh
            const float* pp = pHs + (h * 7 + i) * 8;
            float4 p0 = *(const float4*)pp;
            float4 p1 = *(const float4*)(pp + 4);
            acc[h * 7 + i] += p0.x * vh[0] + p0.y * vh[1] + p0.z * vh[2] +
                              p0.w * vh[3] + p1.x * vh[4] + p1.y * vh[5] +
                              p1.z * vh[6];
        }
        #pragma unroll
        for (int w = 0; w < 7; ++w) {           // out[c, h=i, w] += pW . vw
            const float* pp = pWs + (i * 7 + w) * 8;
            float4 p0 = *(const float4*)pp;
            float4 p1 = *(const float4*)(pp + 4);
            acc[i * 7 + w] += p0.x * vw[0] + p0.y * vw[1] + p0.z * vw[2] +
                              p0.w * vw[3] + p1.x * vw[4] + p1.y * vw[5] +
                              p1.z * vw[6];
        }
        __syncthreads();   // next buffer landed; cur reads done before overwrite
    }

    // ---- Phase E: transpose acc through LDS, coalesced float4 stores ----
    float* outn = out + n * V_SLICE;
    #pragma unroll
    for (int half = 0; half < 2; ++half) {
        if ((t >> 8) == half) {
            float* wb = V + (t & 255) * 51;
            #pragma unroll
            for (int k = 0; k < 49; ++k) wb[k] = acc[k];
        }
        __syncthreads();
        #pragma unroll
        for (int k = 0; k < 7; ++k) {
            int f4 = t + 512 * k;
            if (f4 < 3136) {
                int f = f4 * 4;
                float4 o;
                #pragma unroll
                for (int u = 0; u < 4; ++u) {
                    int e  = f + u;
                    int c  = e / 49;
                    int hw = e - c * 49;
                    ((float*)&o)[u] = V[c * 51 + hw];
                }
                *(float4*)(outn + half * 12544 + f) = o;
            }
        }
        __syncthreads();
    }
}

extern "C" void kernel_launch(void* const* d_in, const int* in_sizes, int n_in,
                              void* d_out, int out_size, void* d_ws, size_t ws_size,
                              hipStream_t stream) {
    const float* qH = (const float*)d_in[0];
    const float* kH = (const float*)d_in[1];
    const float* vH = (const float*)d_in[2];
    const float* qW = (const float*)d_in[3];
    const float* kW = (const float*)d_in[4];
    const float* vW = (const float*)d_in[5];
    float* out = (float*)d_out;
    fused_axial<<<512, 512, 0, stream>>>(qH, kH, vH, qW, kW, vW, out);
}